// Round 1
// baseline (1199.824 us; speedup 1.0000x reference)
//
#include <hip/hip_runtime.h>

// Problem constants (from reference)
#define B_SZ   8192
#define KOBJ   6
#define VD     2048
#define QD     1024
#define NHID_  1024
#define SEIN   128
#define M_TOT  (B_SZ * KOBJ)   // 49152
#define K_TOT  (VD + QD)       // 3072

typedef __bf16 bf16x8 __attribute__((ext_vector_type(8)));
typedef float  f32x4  __attribute__((ext_vector_type(4)));
typedef unsigned int uint4v __attribute__((ext_vector_type(4)));

__device__ __forceinline__ unsigned short f2bf(float f) {
    unsigned u = __builtin_bit_cast(unsigned, f);
    u += 0x7fffu + ((u >> 16) & 1u);   // RNE (inputs are finite/normal)
    return (unsigned short)(u >> 16);
}

// ---------------------------------------------------------------- W1 -> bf16
__global__ __launch_bounds__(256) void conv_w1(const float* __restrict__ W1,
                                               unsigned short* __restrict__ W1b,
                                               int n4) {
    int i = blockIdx.x * 256 + threadIdx.x;
    if (i < n4) {
        float4 f = ((const float4*)W1)[i];
        unsigned lo = (unsigned)f2bf(f.x) | ((unsigned)f2bf(f.y) << 16);
        unsigned hi = (unsigned)f2bf(f.z) | ((unsigned)f2bf(f.w) << 16);
        ((uint2*)W1b)[i] = make_uint2(lo, hi);
    }
}

// ------------------------------------------------- fused GEMM + ReLU + Wl-dot
// logits[m] += sum_n Wl[n] * relu( sum_k A[m,k]*W1[n,k] + b1[n] )
// A[m,k] = (k < VD) ? v[m*VD + k] : q[(m/6)*QD + k-VD]   (converted to bf16)
#define LDA 40   // 32 + 8 pad (2-way LDS conflicts only)
__global__ __launch_bounds__(256) void gemm_logits(
    const float* __restrict__ v, const float* __restrict__ q,
    const unsigned short* __restrict__ W1b,
    const float* __restrict__ b1, const float* __restrict__ Wl,
    float* __restrict__ logits)
{
    __shared__ unsigned short At[128 * LDA];
    __shared__ unsigned short Bt[128 * LDA];

    const int tid  = threadIdx.x;
    const int bid  = blockIdx.x;
    const int nb   = bid & 7;        // n fastest -> 8 N-blocks of an M-chunk run together (L3 reuse of A)
    const int mb   = bid >> 3;
    const int m0   = mb * 128;
    const int n0   = nb * 128;
    const int wave = tid >> 6, lane = tid & 63;
    const int quad = lane >> 4, l16 = lane & 15;
    const int wr   = (wave >> 1) * 64, wc = (wave & 1) * 64;

    f32x4 acc[4][4] = {};

    for (int kk = 0; kk < K_TOT; kk += 32) {
        __syncthreads();
        // ---- stage A tile 128x32 (fp32 -> bf16 in-register)
        const bool isq = (kk >= VD);
        #pragma unroll
        for (int it = 0; it < 4; ++it) {
            int s   = tid + it * 256;          // 0..1023
            int row = s >> 3, c4 = s & 7;
            int m   = m0 + row;
            const float* src = isq ? (q + (size_t)(m / KOBJ) * QD + (kk - VD) + c4 * 4)
                                   : (v + (size_t)m * VD + kk + c4 * 4);
            float4 f = *(const float4*)src;
            unsigned lo = (unsigned)f2bf(f.x) | ((unsigned)f2bf(f.y) << 16);
            unsigned hi = (unsigned)f2bf(f.z) | ((unsigned)f2bf(f.w) << 16);
            *(uint2*)&At[row * LDA + c4 * 4] = make_uint2(lo, hi);
        }
        // ---- stage B tile 128x32 (already bf16, 16B chunks)
        #pragma unroll
        for (int it = 0; it < 2; ++it) {
            int s  = tid + it * 256;           // 0..511
            int n  = s >> 2, kg = s & 3;
            uint4v d = *(const uint4v*)(W1b + (size_t)(n0 + n) * K_TOT + kk + kg * 8);
            *(uint4v*)&Bt[n * LDA + kg * 8] = d;
        }
        __syncthreads();
        // ---- fragments + 16 MFMA
        bf16x8 af[4], bfr[4];
        #pragma unroll
        for (int i = 0; i < 4; ++i)
            af[i] = __builtin_bit_cast(bf16x8, *(const uint4v*)&At[(wr + i * 16 + l16) * LDA + quad * 8]);
        #pragma unroll
        for (int j = 0; j < 4; ++j)
            bfr[j] = __builtin_bit_cast(bf16x8, *(const uint4v*)&Bt[(wc + j * 16 + l16) * LDA + quad * 8]);
        #pragma unroll
        for (int i = 0; i < 4; ++i)
            #pragma unroll
            for (int j = 0; j < 4; ++j)
                acc[i][j] = __builtin_amdgcn_mfma_f32_16x16x32_bf16(af[i], bfr[j], acc[i][j], 0, 0, 0);
    }

    // ---- epilogue: +b1, relu, dot with Wl over this block's 128 cols
    #pragma unroll
    for (int i = 0; i < 4; ++i) {
        #pragma unroll
        for (int r = 0; r < 4; ++r) {
            int m = m0 + wr + i * 16 + quad * 4 + r;
            float sum = 0.f;
            #pragma unroll
            for (int j = 0; j < 4; ++j) {
                int n = n0 + wc + j * 16 + l16;
                float h = fmaxf(acc[i][j][r] + b1[n], 0.f);
                sum = fmaf(h, Wl[n], sum);
            }
            sum += __shfl_xor(sum, 1);
            sum += __shfl_xor(sum, 2);
            sum += __shfl_xor(sum, 4);
            sum += __shfl_xor(sum, 8);
            if (l16 == 0) atomicAdd(&logits[m], sum);
        }
    }
}

// ---------------------------------------- per-b: softmax + mask + SE gate + s
__global__ __launch_bounds__(256) void se_kernel(
    const float* __restrict__ logits, const float* __restrict__ mask,
    const float* __restrict__ bl,
    const float* __restrict__ Wse1, const float* __restrict__ Wse2,
    float* __restrict__ out_att, float* __restrict__ s_buf)
{
    int b = blockIdx.x * 256 + threadIdx.x;
    if (b >= B_SZ) return;
    float w[KOBJ];
    float blv = bl[0];
    #pragma unroll
    for (int k = 0; k < KOBJ; ++k) w[k] = logits[b * KOBJ + k] + blv;

    // softmax over K
    float mx = w[0];
    #pragma unroll
    for (int k = 1; k < KOBJ; ++k) mx = fmaxf(mx, w[k]);
    float e[KOBJ], den = 0.f;
    #pragma unroll
    for (int k = 0; k < KOBJ; ++k) { e[k] = __expf(w[k] - mx); den += e[k]; }
    float rden = 1.f / den;
    #pragma unroll
    for (int k = 0; k < KOBJ; ++k) out_att[b * KOBJ + k] = e[k] * rden;

    // masked complement sum
    float wc[KOBJ], tot = 0.f;
    #pragma unroll
    for (int k = 0; k < KOBJ; ++k) { wc[k] = w[k] * mask[b * KOBJ + k]; tot += wc[k]; }

    #pragma unroll
    for (int k = 0; k < KOBJ; ++k) {
        float x = tot - wc[k];
        float a = 0.f;
        for (int i = 0; i < SEIN; ++i)
            a = fmaf(fmaxf(x * Wse1[i], 0.f), Wse2[i], a);
        float y = 1.f / (1.f + __expf(-a));
        s_buf[b * KOBJ + k] = x * (1.f - y) + w[k];
    }
}

// ------------------------------------------- out2[m,d] = s[m]*Wf[d] + bf[d]
__global__ __launch_bounds__(256) void out_writer(
    const float* __restrict__ s_buf, const float* __restrict__ Wf,
    const float* __restrict__ bfv, float* __restrict__ out)
{
    int m = blockIdx.x;
    float s = s_buf[m];
    const float4* wf4 = (const float4*)Wf;
    const float4* bf4 = (const float4*)bfv;
    float4* o4 = (float4*)(out + (size_t)m * VD);
    #pragma unroll
    for (int it = 0; it < VD / 4 / 256; ++it) {
        int t = threadIdx.x + it * 256;
        float4 wv = wf4[t], bv = bf4[t];
        float4 r;
        r.x = fmaf(s, wv.x, bv.x);
        r.y = fmaf(s, wv.y, bv.y);
        r.z = fmaf(s, wv.z, bv.z);
        r.w = fmaf(s, wv.w, bv.w);
        o4[t] = r;
    }
}

extern "C" void kernel_launch(void* const* d_in, const int* in_sizes, int n_in,
                              void* d_out, int out_size, void* d_ws, size_t ws_size,
                              hipStream_t stream) {
    const float* v    = (const float*)d_in[0];
    const float* q    = (const float*)d_in[1];
    const float* mask = (const float*)d_in[2];
    const float* W1   = (const float*)d_in[3];
    const float* b1   = (const float*)d_in[4];
    const float* Wl   = (const float*)d_in[5];
    const float* bl   = (const float*)d_in[6];
    const float* Wse1 = (const float*)d_in[7];
    const float* Wse2 = (const float*)d_in[8];
    const float* Wf   = (const float*)d_in[9];
    const float* bfv  = (const float*)d_in[10];
    float* out = (float*)d_out;

    // workspace layout (~6.7 MB total)
    char* ws = (char*)d_ws;
    unsigned short* W1b = (unsigned short*)ws;                       // 1024*3072*2 = 6291456 B
    float* logits = (float*)(ws + 6291456);                          // 49152*4
    float* s_buf  = (float*)(ws + 6291456 + 196608);                 // 49152*4

    hipMemsetAsync(logits, 0, M_TOT * sizeof(float), stream);
    conv_w1<<<(NHID_ * K_TOT / 4 + 255) / 256, 256, 0, stream>>>(W1, W1b, NHID_ * K_TOT / 4);
    gemm_logits<<<(M_TOT / 128) * (NHID_ / 128), 256, 0, stream>>>(v, q, W1b, b1, Wl, logits);
    se_kernel<<<(B_SZ + 255) / 256, 256, 0, stream>>>(logits, mask, bl, Wse1, Wse2, out, s_buf);
    out_writer<<<M_TOT, 256, 0, stream>>>(s_buf, Wf, bfv, out + M_TOT);
}

// Round 2
// 1097.684 us; speedup vs baseline: 1.0930x; 1.0930x over previous
//
#include <hip/hip_runtime.h>

#define B_SZ   8192
#define KOBJ   6
#define VD     2048
#define QD     1024
#define NHID_  1024
#define SEIN   128
#define M_TOT  (B_SZ * KOBJ)   // 49152
#define K_TOT  (VD + QD)       // 3072

typedef __bf16 bf16x8 __attribute__((ext_vector_type(8)));
typedef float  f32x4  __attribute__((ext_vector_type(4)));
typedef unsigned int uint4v __attribute__((ext_vector_type(4)));

__device__ __forceinline__ unsigned short f2bf(float f) {
    unsigned u = __builtin_bit_cast(unsigned, f);
    u += 0x7fffu + ((u >> 16) & 1u);   // RNE
    return (unsigned short)(u >> 16);
}

// -------------------------------------------------- fp32 -> bf16 (8 elem/thr)
__global__ __launch_bounds__(256) void conv_bf16(const float* __restrict__ src,
                                                 unsigned short* __restrict__ dst,
                                                 int n8) {
    int i = blockIdx.x * 256 + threadIdx.x;
    if (i < n8) {
        float4 f0 = ((const float4*)src)[2 * i];
        float4 f1 = ((const float4*)src)[2 * i + 1];
        uint4v d;
        d[0] = (unsigned)f2bf(f0.x) | ((unsigned)f2bf(f0.y) << 16);
        d[1] = (unsigned)f2bf(f0.z) | ((unsigned)f2bf(f0.w) << 16);
        d[2] = (unsigned)f2bf(f1.x) | ((unsigned)f2bf(f1.y) << 16);
        d[3] = (unsigned)f2bf(f1.z) | ((unsigned)f2bf(f1.w) << 16);
        ((uint4v*)dst)[i] = d;
    }
}

// ------------------------------------------------- fused GEMM + ReLU + Wl-dot
// m97-style: global_load_lds width-16 staging, no pad (DMA needs contiguous),
// XOR chunk swizzle folded into the GLOBAL fetch address so ds_read_b128
// fragment reads land 2-way (free) instead of 8-way on the 32 banks.
__global__ __launch_bounds__(256) void gemm_logits(
    const unsigned short* __restrict__ vb, const unsigned short* __restrict__ qb,
    const unsigned short* __restrict__ W1b,
    const float* __restrict__ b1, const float* __restrict__ Wl,
    float* __restrict__ logits)
{
    __shared__ unsigned short At[128 * 32];
    __shared__ unsigned short Bt[128 * 32];

    const int tid  = threadIdx.x;
    const int bid  = blockIdx.x;
    const int nb   = bid & 7;        // n fastest -> 8 N-blocks share A rows in L3
    const int mb   = bid >> 3;
    const int m0   = mb * 128;
    const int n0   = nb * 128;
    const int wave = tid >> 6, lane = tid & 63;
    const int quad = lane >> 4, l16 = lane & 15;
    const int wr   = (wave >> 1) * 64, wc = (wave & 1) * 64;

    // staging geometry: seg = wave*2+c covers rows seg*16..seg*16+15;
    // lane supplies 16B: row = seg*16 + (lane>>2), LDS pos (lane&3),
    // fetched global chunk = (lane&3) ^ ((row>>1)&3)   [the swizzle]
    int rowA[2], chA[2];
    const unsigned short* gav[2];
    const unsigned short* gaq[2];
    const unsigned short* gb[2];
    unsigned short* ldsA[2];
    unsigned short* ldsB[2];
    #pragma unroll
    for (int c = 0; c < 2; ++c) {
        int seg = wave * 2 + c;
        rowA[c] = seg * 16 + (lane >> 2);
        chA[c]  = (lane & 3) ^ ((rowA[c] >> 1) & 3);
        int m   = m0 + rowA[c];
        gav[c]  = vb + (size_t)m * VD + chA[c] * 8;
        gaq[c]  = qb + (size_t)(m / KOBJ) * QD + chA[c] * 8;
        gb[c]   = W1b + (size_t)(n0 + rowA[c]) * K_TOT + chA[c] * 8;
        ldsA[c] = &At[seg * 512];   // 16 rows * 32 elem
        ldsB[c] = &Bt[seg * 512];
    }

    f32x4 acc[4][4] = {};
    const int swz = (l16 >> 1) & 3;   // fragment-read swizzle (row-derived)

    for (int kk = 0; kk < K_TOT; kk += 32) {
        __syncthreads();
        const bool isq = (kk >= VD);
        #pragma unroll
        for (int c = 0; c < 2; ++c) {
            const unsigned short* g = isq ? (gaq[c] + (kk - VD)) : (gav[c] + kk);
            __builtin_amdgcn_global_load_lds(
                (const __attribute__((address_space(1))) void*)g,
                (__attribute__((address_space(3))) void*)ldsA[c], 16, 0, 0);
        }
        #pragma unroll
        for (int c = 0; c < 2; ++c) {
            const unsigned short* g = gb[c] + kk;
            __builtin_amdgcn_global_load_lds(
                (const __attribute__((address_space(1))) void*)g,
                (__attribute__((address_space(3))) void*)ldsB[c], 16, 0, 0);
        }
        __syncthreads();   // compiler inserts s_waitcnt vmcnt(0) before barrier

        bf16x8 af[4], bfr[4];
        #pragma unroll
        for (int i = 0; i < 4; ++i)
            af[i] = __builtin_bit_cast(bf16x8,
                *(const uint4v*)&At[(wr + i * 16 + l16) * 32 + ((quad ^ swz) * 8)]);
        #pragma unroll
        for (int j = 0; j < 4; ++j)
            bfr[j] = __builtin_bit_cast(bf16x8,
                *(const uint4v*)&Bt[(wc + j * 16 + l16) * 32 + ((quad ^ swz) * 8)]);
        #pragma unroll
        for (int i = 0; i < 4; ++i)
            #pragma unroll
            for (int j = 0; j < 4; ++j)
                acc[i][j] = __builtin_amdgcn_mfma_f32_16x16x32_bf16(af[i], bfr[j], acc[i][j], 0, 0, 0);
    }

    // epilogue: +b1, relu, dot with Wl over this block's 128 cols
    #pragma unroll
    for (int i = 0; i < 4; ++i) {
        #pragma unroll
        for (int r = 0; r < 4; ++r) {
            int m = m0 + wr + i * 16 + quad * 4 + r;
            float sum = 0.f;
            #pragma unroll
            for (int j = 0; j < 4; ++j) {
                int n = n0 + wc + j * 16 + l16;
                float h = fmaxf(acc[i][j][r] + b1[n], 0.f);
                sum = fmaf(h, Wl[n], sum);
            }
            sum += __shfl_xor(sum, 1);
            sum += __shfl_xor(sum, 2);
            sum += __shfl_xor(sum, 4);
            sum += __shfl_xor(sum, 8);
            if (l16 == 0) atomicAdd(&logits[m], sum);
        }
    }
}

// ---------------------------------------- per-b: softmax + mask + SE gate + s
__global__ __launch_bounds__(256) void se_kernel(
    const float* __restrict__ logits, const float* __restrict__ mask,
    const float* __restrict__ bl,
    const float* __restrict__ Wse1, const float* __restrict__ Wse2,
    float* __restrict__ out_att, float* __restrict__ s_buf)
{
    int b = blockIdx.x * 256 + threadIdx.x;
    if (b >= B_SZ) return;
    float w[KOBJ];
    float blv = bl[0];
    #pragma unroll
    for (int k = 0; k < KOBJ; ++k) w[k] = logits[b * KOBJ + k] + blv;

    float mx = w[0];
    #pragma unroll
    for (int k = 1; k < KOBJ; ++k) mx = fmaxf(mx, w[k]);
    float e[KOBJ], den = 0.f;
    #pragma unroll
    for (int k = 0; k < KOBJ; ++k) { e[k] = __expf(w[k] - mx); den += e[k]; }
    float rden = 1.f / den;
    #pragma unroll
    for (int k = 0; k < KOBJ; ++k) out_att[b * KOBJ + k] = e[k] * rden;

    float wcm[KOBJ], tot = 0.f;
    #pragma unroll
    for (int k = 0; k < KOBJ; ++k) { wcm[k] = w[k] * mask[b * KOBJ + k]; tot += wcm[k]; }

    #pragma unroll
    for (int k = 0; k < KOBJ; ++k) {
        float x = tot - wcm[k];
        float a = 0.f;
        for (int i = 0; i < SEIN; ++i)
            a = fmaf(fmaxf(x * Wse1[i], 0.f), Wse2[i], a);
        float y = 1.f / (1.f + __expf(-a));
        s_buf[b * KOBJ + k] = x * (1.f - y) + w[k];
    }
}

// ------------------------------------------- out2[m,d] = s[m]*Wf[d] + bf[d]
__global__ __launch_bounds__(256) void out_writer(
    const float* __restrict__ s_buf, const float* __restrict__ Wf,
    const float* __restrict__ bfv, float* __restrict__ out)
{
    int m = blockIdx.x;
    float s = s_buf[m];
    const float4* wf4 = (const float4*)Wf;
    const float4* bf4 = (const float4*)bfv;
    float4* o4 = (float4*)(out + (size_t)m * VD);
    #pragma unroll
    for (int it = 0; it < VD / 4 / 256; ++it) {
        int t = threadIdx.x + it * 256;
        float4 wv = wf4[t], bv = bf4[t];
        float4 r;
        r.x = fmaf(s, wv.x, bv.x);
        r.y = fmaf(s, wv.y, bv.y);
        r.z = fmaf(s, wv.z, bv.z);
        r.w = fmaf(s, wv.w, bv.w);
        o4[t] = r;
    }
}

extern "C" void kernel_launch(void* const* d_in, const int* in_sizes, int n_in,
                              void* d_out, int out_size, void* d_ws, size_t ws_size,
                              hipStream_t stream) {
    const float* v    = (const float*)d_in[0];
    const float* q    = (const float*)d_in[1];
    const float* mask = (const float*)d_in[2];
    const float* W1   = (const float*)d_in[3];
    const float* b1   = (const float*)d_in[4];
    const float* Wl   = (const float*)d_in[5];
    const float* bl   = (const float*)d_in[6];
    const float* Wse1 = (const float*)d_in[7];
    const float* Wse2 = (const float*)d_in[8];
    const float* Wf   = (const float*)d_in[9];
    const float* bfv  = (const float*)d_in[10];
    float* out = (float*)d_out;

    // ws: W1b bf16 (6 MB) + logits + s_buf  (~6.7 MB, known to fit)
    char* ws = (char*)d_ws;
    unsigned short* W1b = (unsigned short*)ws;                       // 6291456 B
    float* logits = (float*)(ws + 6291456);                          // 196608 B
    float* s_buf  = (float*)(ws + 6291456 + 196608);                 // 196608 B

    // Scratch for bf16 A lives in the TAIL of d_out (out2 region, 402 MB):
    // fully consumed by gemm before out_writer overwrites it.
    unsigned short* vb = (unsigned short*)((char*)d_out + (size_t)M_TOT * 4);
    unsigned short* qb = (unsigned short*)((char*)d_out + (size_t)M_TOT * 4 + 201326592);

    hipMemsetAsync(logits, 0, M_TOT * sizeof(float), stream);
    conv_bf16<<<(NHID_ * K_TOT / 8 + 255) / 256, 256, 0, stream>>>(W1, W1b, NHID_ * K_TOT / 8);
    conv_bf16<<<(M_TOT * VD / 8 + 255) / 256, 256, 0, stream>>>(v, vb, M_TOT * VD / 8);
    conv_bf16<<<(B_SZ * QD / 8 + 255) / 256, 256, 0, stream>>>(q, qb, B_SZ * QD / 8);
    gemm_logits<<<(M_TOT / 128) * (NHID_ / 128), 256, 0, stream>>>(vb, qb, W1b, b1, Wl, logits);
    se_kernel<<<(B_SZ + 255) / 256, 256, 0, stream>>>(logits, mask, bl, Wse1, Wse2, out, s_buf);
    out_writer<<<M_TOT, 256, 0, stream>>>(s_buf, Wf, bfv, out + M_TOT);
}